// Round 13
// baseline (279.335 us; speedup 1.0000x reference)
//
#include <hip/hip_runtime.h>
#include <hip/hip_bf16.h>

#define NN 100000
#define EE 1600000
#define HH 32
#define GG 512
#define FIN 7
#define NBUK 391        // ceil(NN/256): coarse buckets of 256 nodes
#define EPB 2048        // edges per p1 block
#define P1G 782         // ceil(EE/EPB)
#define BCAP 4608       // per-bucket capacity (mean 4096, +8 sigma)
#define SLOPE 0.22916666666666666f
#define QS 32767.0f
#define IQS (1.0f / 32767.0f)
#define RMASK 0x1FFFFu

typedef unsigned short bf16_t;
typedef unsigned int uint32;
typedef unsigned long long uint64;
typedef unsigned short u16v2 __attribute__((ext_vector_type(2)));

__device__ __forceinline__ bf16_t f2b(float f) {
    return (bf16_t)(__bfloat16_as_ushort(__float2bfloat16(f)));
}
__device__ __forceinline__ float b2f(bf16_t u) {
    return __uint_as_float(((uint32)u) << 16);
}
__device__ __forceinline__ float lo16(uint32 u) { return __uint_as_float(u << 16); }
__device__ __forceinline__ float hi16(uint32 u) { return __uint_as_float(u & 0xFFFF0000u); }
__device__ __forceinline__ uint32 pack2(float a, float b) {
    return (uint32)f2b(a) | ((uint32)f2b(b) << 16);
}
// order-preserving bf16<->u16 transform (per packed pair)
__device__ __forceinline__ uint32 fwd16(uint32 u) {
    return u ^ (0x80008000u | (((u >> 15) & 0x00010001u) * 0x7FFFu));
}
__device__ __forceinline__ uint32 inv16(uint32 w) {
    return w ^ (0x80008000u | ((((~w) >> 15) & 0x00010001u) * 0x7FFFu));
}
__device__ __forceinline__ uint32 pkmax(uint32 a, uint32 b) {
    u16v2 x = __builtin_bit_cast(u16v2, a);
    u16v2 y = __builtin_bit_cast(u16v2, b);
    u16v2 r = __builtin_elementwise_max(x, y);
    return __builtin_bit_cast(uint32, r);
}

// ---- p1: local counting sort by coarse bucket; block-private coalesced dump.
__global__ __launch_bounds__(256) void k_p1(const int* __restrict__ row,
                                            const int* __restrict__ col,
                                            const float* __restrict__ ew,
                                            int* __restrict__ Pmat,
                                            uint64* __restrict__ pay) {
    __shared__ int h[512];
    __shared__ int cur[392];
    int t = threadIdx.x;
    h[t] = 0; h[t + 256] = 0;
    __syncthreads();
    int e0 = blockIdx.x * EPB, e1 = min(e0 + EPB, EE);
    for (int e = e0 + t; e < e1; e += 256) atomicAdd(&h[col[e] >> 8], 1);
    __syncthreads();
    int c0 = h[t], c1 = h[t + 256];
    for (int d = 1; d < 512; d <<= 1) {
        int a = (t >= d) ? h[t - d] : 0;
        int b = h[t + 256 - d];
        __syncthreads();
        h[t] += a; h[t + 256] += b;
        __syncthreads();
    }
    int ex0 = h[t] - c0, ex1 = h[t + 256] - c1;
    if (t < 392) { cur[t] = ex0; Pmat[blockIdx.x * 392 + t] = ex0; }
    if (t + 256 < 392) { cur[t + 256] = ex1; Pmat[blockIdx.x * 392 + t + 256] = ex1; }
    __syncthreads();
    uint64* bpay = pay + (size_t)blockIdx.x * EPB;
    for (int e = e0 + t; e < e1; e += 256) {
        int c = col[e];
        int b = c >> 8;
        uint32 q = (uint32)(ew[e] * QS + 0.5f);
        int r = atomicAdd(&cur[b], 1);             // LDS cursor only
        bpay[r] = ((uint64)(uint32)(c & 255) << 32) | ((uint64)q << 17) | (uint32)row[e];
    }
}

// ---- p2: gather bucket runs via Pmat, in-LDS counting sort -> spack + dis/xsu
__global__ __launch_bounds__(256) void k_p2(const int* __restrict__ Pmat,
                                            const uint64* __restrict__ pay,
                                            const float* __restrict__ x,
                                            uint32* __restrict__ spack,
                                            int* __restrict__ cnt,
                                            int* __restrict__ off,
                                            float* __restrict__ d1s,
                                            float* __restrict__ d2,
                                            uint32* __restrict__ xsu) {
    __shared__ uint64 staged[BCAP];
    __shared__ int hist[256], s[256], cur[256], qsum[256];
    __shared__ int tot;
    int b = blockIdx.x, t = threadIdx.x;
    hist[t] = 0; qsum[t] = 0;
    if (t == 0) tot = 0;
    __syncthreads();
    for (int k = t; k < P1G; k += 256) {
        int s0 = Pmat[k * 392 + b];
        int s1 = Pmat[k * 392 + b + 1];
        int len = s1 - s0;
        if (len > 0) {
            int r0 = atomicAdd(&tot, len);
            const uint64* src = pay + (size_t)k * EPB + s0;
            for (int i = 0; i < len && r0 + i < BCAP; i++) staged[r0 + i] = src[i];
        }
    }
    __syncthreads();
    int M = min(tot, BCAP);
    for (int j = t; j < M; j += 256) atomicAdd(&hist[(int)(staged[j] >> 32)], 1);
    __syncthreads();
    int v = hist[t]; s[t] = v;
    __syncthreads();
    for (int d = 1; d < 256; d <<= 1) {
        int u = (t >= d) ? s[t - d] : 0;
        __syncthreads();
        s[t] += u;
        __syncthreads();
    }
    int excl = s[t] - v;
    int gb = b * BCAP;
    int n = b * 256 + t;
    if (n < NN) { cnt[n] = v; off[n] = gb + excl; }
    cur[t] = excl;
    __syncthreads();
    for (int j = t; j < M; j += 256) {
        uint64 p = staged[j];
        int nb = (int)(p >> 32);
        int r = atomicAdd(&cur[nb], 1);
        spack[gb + r] = (uint32)p;
        atomicAdd(&qsum[nb], (int)((uint32)p >> 17));
    }
    __syncthreads();
    if (n < NN) {
        int sq = qsum[t];
        float dis1 = sq > 0 ? rsqrtf((float)sq * IQS) : 0.0f;
        d1s[n] = dis1 * IQS;
        d2[n] = v > 0 ? rsqrtf((float)v) : 0.0f;
        float f0 = x[n * FIN + 0] * dis1, f1 = x[n * FIN + 1] * dis1;
        float f2 = x[n * FIN + 2] * dis1, f3 = x[n * FIN + 3] * dis1;
        float f4 = x[n * FIN + 4] * dis1, f5 = x[n * FIN + 5] * dis1;
        float f6 = x[n * FIN + 6] * dis1;
        xsu[n * 4 + 0] = pack2(f0, f1);
        xsu[n * 4 + 1] = pack2(f2, f3);
        xsu[n * 4 + 2] = pack2(f4, f5);
        xsu[n * 4 + 3] = pack2(f6, 0.0f);
    }
}

// ---- conv1: lane-per-edge gather; W1 post-sum; x1u written TRANSFORMED ---
__global__ __launch_bounds__(256) void k_agg1(const int* __restrict__ off,
                                              const int* __restrict__ cnt,
                                              const uint32* __restrict__ spack,
                                              const uint4* __restrict__ XS,
                                              const float* __restrict__ d1s,
                                              const float* __restrict__ b1,
                                              const float* __restrict__ W1,
                                              uint32* __restrict__ x1u) {
    __shared__ float sW[FIN * HH];
    int t = threadIdx.x;
    if (t < FIN * HH) sW[t] = W1[t];
    __syncthreads();
    int n = blockIdx.x * 16 + (t >> 4);
    int l = t & 15;
    int o = off[n], m = cnt[n];
    const uint32* bin = spack + o;
    float a0 = 0, a1 = 0, a2 = 0, a3 = 0, a4 = 0, a5 = 0, a6 = 0;
    for (int j = l; j < m; j += 16) {
        uint32 p = bin[j];
        uint4 v = XS[p & RMASK];
        float q = (float)(p >> 17);
        a0 += q * lo16(v.x); a1 += q * hi16(v.x);
        a2 += q * lo16(v.y); a3 += q * hi16(v.y);
        a4 += q * lo16(v.z); a5 += q * hi16(v.z);
        a6 += q * lo16(v.w);
    }
#pragma unroll
    for (int q = 8; q >= 1; q >>= 1) {
        a0 += __shfl_xor(a0, q, 16); a1 += __shfl_xor(a1, q, 16);
        a2 += __shfl_xor(a2, q, 16); a3 += __shfl_xor(a3, q, 16);
        a4 += __shfl_xor(a4, q, 16); a5 += __shfl_xor(a5, q, 16);
        a6 += __shfl_xor(a6, q, 16);
    }
    float sc = d1s[n];
    int c0 = 2 * l, c1 = 2 * l + 1;
    float s0 = a0 * sW[c0] + a1 * sW[HH + c0] + a2 * sW[2 * HH + c0]
             + a3 * sW[3 * HH + c0] + a4 * sW[4 * HH + c0]
             + a5 * sW[5 * HH + c0] + a6 * sW[6 * HH + c0];
    float s1 = a0 * sW[c1] + a1 * sW[HH + c1] + a2 * sW[2 * HH + c1]
             + a3 * sW[3 * HH + c1] + a4 * sW[4 * HH + c1]
             + a5 * sW[5 * HH + c1] + a6 * sW[6 * HH + c1];
    x1u[n * 16 + l] = fwd16(pack2(sc * s0 + b1[c0], sc * s1 + b1[c1]));
}

// ---- neighbor max-pool: wave=node, packed u16 max (2 ch/instr) -----------
__global__ __launch_bounds__(256) void k_pool(const int* __restrict__ off,
                                              const int* __restrict__ cnt,
                                              const uint32* __restrict__ spack,
                                              const uint32* __restrict__ X1,
                                              const float* __restrict__ d2,
                                              uint32* __restrict__ xpu,
                                              uint32* __restrict__ xpsu) {
    int t = threadIdx.x;
    int n = blockIdx.x * 4 + (t >> 6);
    int l = t & 63;
    int eg = l >> 2, qt = l & 3;
    int o = off[n], m = cnt[n];
    const uint32* bin = spack + o;
    const uint4* X4 = (const uint4*)X1;
    uint4 u = X4[n * 4 + qt];          // transformed self quarter
    uint32 t0 = u.x, t1 = u.y, t2 = u.z, t3 = u.w;
    for (int j0 = 0; j0 < m; j0 += 16) {
        int j = j0 + eg;
        int r = (j < m) ? (int)(bin[j] & RMASK) : n;   // self = identity
        uint4 v = X4[r * 4 + qt];
        t0 = pkmax(t0, v.x); t1 = pkmax(t1, v.y);
        t2 = pkmax(t2, v.z); t3 = pkmax(t3, v.w);
    }
#pragma unroll
    for (int o2 = 4; o2 < 64; o2 <<= 1) {
        t0 = pkmax(t0, (uint32)__shfl_xor((int)t0, o2, 64));
        t1 = pkmax(t1, (uint32)__shfl_xor((int)t1, o2, 64));
        t2 = pkmax(t2, (uint32)__shfl_xor((int)t2, o2, 64));
        t3 = pkmax(t3, (uint32)__shfl_xor((int)t3, o2, 64));
    }
    if (eg == 0) {
        uint32 r0 = inv16(t0), r1 = inv16(t1), r2 = inv16(t2), r3 = inv16(t3);
        float dn = d2[n];
        uint4 w0, w1;
        w0.x = r0; w0.y = r1; w0.z = r2; w0.w = r3;            // bf16 maxima: exact
        w1.x = pack2(dn * lo16(r0), dn * hi16(r0));
        w1.y = pack2(dn * lo16(r1), dn * hi16(r1));
        w1.z = pack2(dn * lo16(r2), dn * hi16(r2));
        w1.w = pack2(dn * lo16(r3), dn * hi16(r3));
        ((uint4*)xpu)[n * 4 + qt] = w0;
        ((uint4*)xpsu)[n * 4 + qt] = w1;
    }
}

// ---- conv2 gather-sum + FUSED W2 matmul + relu(residual) -> xnh ----------
// wave = node; after butterfly the 4 eg==0 lanes stage S[32] through LDS,
// then lanes 0..31 apply W2 (LDS), add xp residual + b2, relu, write bf16.
// Arithmetic identical to old k_agg2 + k_xn (same summation order).
__global__ __launch_bounds__(256) void k_agg2xn(const int* __restrict__ off,
                                                const int* __restrict__ cnt,
                                                const uint32* __restrict__ spack,
                                                const uint32* __restrict__ XPS,
                                                const uint32* __restrict__ xpu,
                                                const float* __restrict__ d2,
                                                const float* __restrict__ b2,
                                                const float* __restrict__ W2,
                                                bf16_t* __restrict__ xnh) {
    __shared__ float sW[HH * HH];
    __shared__ float sxv[4][HH];
    int t = threadIdx.x;
    for (int j = t; j < HH * HH; j += 256) sW[j] = W2[j];
    int w = t >> 6;
    int n = blockIdx.x * 4 + w;
    int l = t & 63;
    int eg = l >> 2, qt = l & 3;
    int o = off[n], m = cnt[n];
    const uint32* bin = spack + o;
    const uint4* X4 = (const uint4*)XPS;
    float a0 = 0, a1 = 0, a2 = 0, a3 = 0, a4 = 0, a5 = 0, a6 = 0, a7 = 0;
    for (int j0 = 0; j0 < m; j0 += 16) {
        int j = j0 + eg;
        if (j < m) {
            uint4 v = X4[(bin[j] & RMASK) * 4 + qt];
            a0 += lo16(v.x); a1 += hi16(v.x);
            a2 += lo16(v.y); a3 += hi16(v.y);
            a4 += lo16(v.z); a5 += hi16(v.z);
            a6 += lo16(v.w); a7 += hi16(v.w);
        }
    }
#pragma unroll
    for (int o2 = 4; o2 < 64; o2 <<= 1) {
        a0 += __shfl_xor(a0, o2, 64); a1 += __shfl_xor(a1, o2, 64);
        a2 += __shfl_xor(a2, o2, 64); a3 += __shfl_xor(a3, o2, 64);
        a4 += __shfl_xor(a4, o2, 64); a5 += __shfl_xor(a5, o2, 64);
        a6 += __shfl_xor(a6, o2, 64); a7 += __shfl_xor(a7, o2, 64);
    }
    if (eg == 0) {
        float* dst = sxv[w] + qt * 8;
        dst[0] = a0; dst[1] = a1; dst[2] = a2; dst[3] = a3;
        dst[4] = a4; dst[5] = a5; dst[6] = a6; dst[7] = a7;
    }
    __syncthreads();
    if (l < HH) {
        int c = l;
        const float* xr = sxv[w];
        float acc = 0.0f;
#pragma unroll
        for (int k = 0; k < HH; k++) acc += xr[k] * sW[k * HH + c];
        uint32 u = xpu[n * 16 + (c >> 1)];
        float xpv = (c & 1) ? hi16(u) : lo16(u);
        xnh[n * HH + c] = f2b(fmaxf(xpv + d2[n] * acc + b2[c], 0.0f));
    }
}

// ---- fused per-graph max-pool + residual MLP head ------------------------
__global__ __launch_bounds__(256) void k_gpool_mlp(const bf16_t* __restrict__ xnh,
                                                   const int* __restrict__ batch,
                                                   const float* __restrict__ Wl1,
                                                   const float* __restrict__ bl1,
                                                   const float* __restrict__ Wl2,
                                                   const float* __restrict__ bl2,
                                                   const float* __restrict__ Wl3,
                                                   const float* __restrict__ bl3,
                                                   float* __restrict__ out) {
    __shared__ float sW1[HH * HH];
    __shared__ float sW2[HH * HH];
    __shared__ float sW3[HH];
    __shared__ float sred[8][HH];
    int t = threadIdx.x;
    int g = blockIdx.x;
    for (int j = t; j < HH * HH; j += 256) {
        sW1[j] = Wl1[j];
        sW2[j] = Wl2[j];
    }
    if (t < HH) sW3[t] = Wl3[t];

    int lo = 0, hi = NN;
    while (lo < hi) { int mid = (lo + hi) >> 1; if (batch[mid] < g) lo = mid + 1; else hi = mid; }
    int s = lo;
    hi = NN;
    while (lo < hi) { int mid = (lo + hi) >> 1; if (batch[mid] < g + 1) lo = mid + 1; else hi = mid; }
    int e = lo;

    int c = t & 31, w = t >> 5;
    float mx = -3.0e38f;
    for (int i = s + w; i < e; i += 8) mx = fmaxf(mx, b2f(xnh[i * HH + c]));
    sred[w][c] = mx;
    __syncthreads();

    if (t < HH) {
        float x0 = sred[0][t];
#pragma unroll
        for (int q = 1; q < 8; q++) x0 = fmaxf(x0, sred[q][t]);
        float acc = 0.0f;
#pragma unroll
        for (int k = 0; k < HH; k++) acc += __shfl(x0, k, 32) * sW1[k * HH + t];
        float a1 = x0 + acc + bl1[t];
        a1 = a1 >= 0.0f ? a1 : SLOPE * a1;
        float acc2 = 0.0f;
#pragma unroll
        for (int k = 0; k < HH; k++) acc2 += __shfl(a1, k, 32) * sW2[k * HH + t];
        float a2 = a1 + acc2 + bl2[t];
        a2 = a2 >= 0.0f ? a2 : SLOPE * a2;
        float p = a2 * sW3[t];
#pragma unroll
        for (int o = 16; o >= 1; o >>= 1) p += __shfl_down(p, o, 32);
        if (t == 0) {
            float o = p + bl3[0];
            o = o >= 0.0f ? o : SLOPE * o;
            out[g] = o;
        }
    }
}

extern "C" void kernel_launch(void* const* d_in, const int* in_sizes, int n_in,
                              void* d_out, int out_size, void* d_ws, size_t ws_size,
                              hipStream_t stream) {
    const float* x   = (const float*)d_in[0];
    const int*   ei  = (const int*)d_in[1];
    const int*   bat = (const int*)d_in[2];
    const float* ew  = (const float*)d_in[3];
    const float* W1  = (const float*)d_in[4];
    const float* b1  = (const float*)d_in[5];
    const float* W2  = (const float*)d_in[6];
    const float* b2  = (const float*)d_in[7];
    const float* Wl1 = (const float*)d_in[8];
    const float* bl1 = (const float*)d_in[9];
    const float* Wl2 = (const float*)d_in[10];
    const float* bl2 = (const float*)d_in[11];
    const float* Wl3 = (const float*)d_in[12];
    const float* bl3 = (const float*)d_in[13];
    float* out = (float*)d_out;

    const int* row = ei;
    const int* col = ei + EE;

    // workspace layout (~47 MB)
    char* w = (char*)d_ws;
    uint64* pay  = (uint64*)w;  w += (size_t)P1G * EPB * 8;    // 12.8 MB
    int*   Pmat  = (int*)w;     w += (size_t)P1G * 392 * 4;    // 1.23 MB
    uint32* spack = (uint32*)w; w += (size_t)NBUK * BCAP * 4;  // 7.2 MB
    int*    cnt  = (int*)w;     w += NN * 4;
    int*    off  = (int*)w;     w += NN * 4;
    float*  d1s  = (float*)w;   w += NN * 4;
    float*  d2   = (float*)w;   w += NN * 4;
    uint32* xsu  = (uint32*)w;  w += (size_t)NN * 4 * 4;       // 1.6 MB
    uint32* x1u  = (uint32*)w;  w += (size_t)NN * 16 * 4;      // 6.4 MB (transformed)
    uint32* xpu  = (uint32*)w;  w += (size_t)NN * 16 * 4;      // 6.4 MB
    uint32* xpsu = (uint32*)w;  w += (size_t)NN * 16 * 4;      // 6.4 MB
    bf16_t* xnh  = (bf16_t*)w;  w += (size_t)NN * HH * 2;      // 6.4 MB

    k_p1     <<<P1G, 256, 0, stream>>>(row, col, ew, Pmat, pay);
    k_p2     <<<NBUK, 256, 0, stream>>>(Pmat, pay, x, spack, cnt, off, d1s, d2, xsu);
    k_agg1   <<<NN / 16, 256, 0, stream>>>(off, cnt, spack, (const uint4*)xsu, d1s, b1, W1, x1u);
    k_pool   <<<NN / 4, 256, 0, stream>>>(off, cnt, spack, x1u, d2, xpu, xpsu);
    k_agg2xn <<<NN / 4, 256, 0, stream>>>(off, cnt, spack, xpsu, xpu, d2, b2, W2, xnh);
    k_gpool_mlp<<<GG, 256, 0, stream>>>(xnh, bat, Wl1, bl1, Wl2, bl2, Wl3, bl3, out);
}

// Round 14
// 262.704 us; speedup vs baseline: 1.0633x; 1.0633x over previous
//
#include <hip/hip_runtime.h>
#include <hip/hip_bf16.h>

#define NN 100000
#define EE 1600000
#define HH 32
#define GG 512
#define FIN 7
#define NBUK 391        // ceil(NN/256): coarse buckets of 256 nodes
#define EPB 2048        // edges per p1 block
#define P1G 782         // ceil(EE/EPB)
#define BCAP 4608       // per-bucket capacity (mean 4096, +8 sigma)
#define SLOPE 0.22916666666666666f
#define QS 32767.0f
#define IQS (1.0f / 32767.0f)
#define RMASK 0x1FFFFu

typedef unsigned short bf16_t;
typedef unsigned int uint32;
typedef unsigned long long uint64;
typedef unsigned short u16v2 __attribute__((ext_vector_type(2)));

__device__ __forceinline__ bf16_t f2b(float f) {
    return (bf16_t)(__bfloat16_as_ushort(__float2bfloat16(f)));
}
__device__ __forceinline__ float b2f(bf16_t u) {
    return __uint_as_float(((uint32)u) << 16);
}
__device__ __forceinline__ float lo16(uint32 u) { return __uint_as_float(u << 16); }
__device__ __forceinline__ float hi16(uint32 u) { return __uint_as_float(u & 0xFFFF0000u); }
__device__ __forceinline__ uint32 pack2(float a, float b) {
    return (uint32)f2b(a) | ((uint32)f2b(b) << 16);
}
// order-preserving bf16<->u16 transform (per packed pair)
__device__ __forceinline__ uint32 fwd16(uint32 u) {
    return u ^ (0x80008000u | (((u >> 15) & 0x00010001u) * 0x7FFFu));
}
__device__ __forceinline__ uint32 inv16(uint32 w) {
    return w ^ (0x80008000u | ((((~w) >> 15) & 0x00010001u) * 0x7FFFu));
}
__device__ __forceinline__ uint32 pkmax(uint32 a, uint32 b) {
    u16v2 x = __builtin_bit_cast(u16v2, a);
    u16v2 y = __builtin_bit_cast(u16v2, b);
    u16v2 r = __builtin_elementwise_max(x, y);
    return __builtin_bit_cast(uint32, r);
}

// ---- p1: local counting sort by coarse bucket; block-private coalesced dump.
__global__ __launch_bounds__(256) void k_p1(const int* __restrict__ row,
                                            const int* __restrict__ col,
                                            const float* __restrict__ ew,
                                            int* __restrict__ Pmat,
                                            uint64* __restrict__ pay) {
    __shared__ int h[512];
    __shared__ int cur[392];
    int t = threadIdx.x;
    h[t] = 0; h[t + 256] = 0;
    __syncthreads();
    int e0 = blockIdx.x * EPB, e1 = min(e0 + EPB, EE);
    for (int e = e0 + t; e < e1; e += 256) atomicAdd(&h[col[e] >> 8], 1);
    __syncthreads();
    int c0 = h[t], c1 = h[t + 256];
    for (int d = 1; d < 512; d <<= 1) {
        int a = (t >= d) ? h[t - d] : 0;
        int b = h[t + 256 - d];
        __syncthreads();
        h[t] += a; h[t + 256] += b;
        __syncthreads();
    }
    int ex0 = h[t] - c0, ex1 = h[t + 256] - c1;
    if (t < 392) { cur[t] = ex0; Pmat[blockIdx.x * 392 + t] = ex0; }
    if (t + 256 < 392) { cur[t + 256] = ex1; Pmat[blockIdx.x * 392 + t + 256] = ex1; }
    __syncthreads();
    uint64* bpay = pay + (size_t)blockIdx.x * EPB;
    for (int e = e0 + t; e < e1; e += 256) {
        int c = col[e];
        int b = c >> 8;
        uint32 q = (uint32)(ew[e] * QS + 0.5f);
        int r = atomicAdd(&cur[b], 1);             // LDS cursor only
        bpay[r] = ((uint64)(uint32)(c & 255) << 32) | ((uint64)q << 17) | (uint32)row[e];
    }
}

// ---- p2: gather bucket runs via Pmat, in-LDS counting sort -> spack + dis/xsu
__global__ __launch_bounds__(256) void k_p2(const int* __restrict__ Pmat,
                                            const uint64* __restrict__ pay,
                                            const float* __restrict__ x,
                                            uint32* __restrict__ spack,
                                            int* __restrict__ cnt,
                                            int* __restrict__ off,
                                            float* __restrict__ d1s,
                                            float* __restrict__ d2,
                                            uint32* __restrict__ xsu) {
    __shared__ uint64 staged[BCAP];
    __shared__ int hist[256], s[256], cur[256], qsum[256];
    __shared__ int tot;
    int b = blockIdx.x, t = threadIdx.x;
    hist[t] = 0; qsum[t] = 0;
    if (t == 0) tot = 0;
    __syncthreads();
    for (int k = t; k < P1G; k += 256) {
        int s0 = Pmat[k * 392 + b];
        int s1 = Pmat[k * 392 + b + 1];
        int len = s1 - s0;
        if (len > 0) {
            int r0 = atomicAdd(&tot, len);
            const uint64* src = pay + (size_t)k * EPB + s0;
            for (int i = 0; i < len && r0 + i < BCAP; i++) staged[r0 + i] = src[i];
        }
    }
    __syncthreads();
    int M = min(tot, BCAP);
    for (int j = t; j < M; j += 256) atomicAdd(&hist[(int)(staged[j] >> 32)], 1);
    __syncthreads();
    int v = hist[t]; s[t] = v;
    __syncthreads();
    for (int d = 1; d < 256; d <<= 1) {
        int u = (t >= d) ? s[t - d] : 0;
        __syncthreads();
        s[t] += u;
        __syncthreads();
    }
    int excl = s[t] - v;
    int gb = b * BCAP;
    int n = b * 256 + t;
    if (n < NN) { cnt[n] = v; off[n] = gb + excl; }
    cur[t] = excl;
    __syncthreads();
    for (int j = t; j < M; j += 256) {
        uint64 p = staged[j];
        int nb = (int)(p >> 32);
        int r = atomicAdd(&cur[nb], 1);
        spack[gb + r] = (uint32)p;
        atomicAdd(&qsum[nb], (int)((uint32)p >> 17));
    }
    __syncthreads();
    if (n < NN) {
        int sq = qsum[t];
        float dis1 = sq > 0 ? rsqrtf((float)sq * IQS) : 0.0f;
        d1s[n] = dis1 * IQS;
        d2[n] = v > 0 ? rsqrtf((float)v) : 0.0f;
        float f0 = x[n * FIN + 0] * dis1, f1 = x[n * FIN + 1] * dis1;
        float f2 = x[n * FIN + 2] * dis1, f3 = x[n * FIN + 3] * dis1;
        float f4 = x[n * FIN + 4] * dis1, f5 = x[n * FIN + 5] * dis1;
        float f6 = x[n * FIN + 6] * dis1;
        xsu[n * 4 + 0] = pack2(f0, f1);
        xsu[n * 4 + 1] = pack2(f2, f3);
        xsu[n * 4 + 2] = pack2(f4, f5);
        xsu[n * 4 + 3] = pack2(f6, 0.0f);
    }
}

// ---- conv1: lane-per-edge gather; W1 post-sum; x1u written TRANSFORMED ---
__global__ __launch_bounds__(256) void k_agg1(const int* __restrict__ off,
                                              const int* __restrict__ cnt,
                                              const uint32* __restrict__ spack,
                                              const uint4* __restrict__ XS,
                                              const float* __restrict__ d1s,
                                              const float* __restrict__ b1,
                                              const float* __restrict__ W1,
                                              uint32* __restrict__ x1u) {
    __shared__ float sW[FIN * HH];
    int t = threadIdx.x;
    if (t < FIN * HH) sW[t] = W1[t];
    __syncthreads();
    int n = blockIdx.x * 16 + (t >> 4);
    int l = t & 15;
    int o = off[n], m = cnt[n];
    const uint32* bin = spack + o;
    float a0 = 0, a1 = 0, a2 = 0, a3 = 0, a4 = 0, a5 = 0, a6 = 0;
    for (int j = l; j < m; j += 16) {
        uint32 p = bin[j];
        uint4 v = XS[p & RMASK];
        float q = (float)(p >> 17);
        a0 += q * lo16(v.x); a1 += q * hi16(v.x);
        a2 += q * lo16(v.y); a3 += q * hi16(v.y);
        a4 += q * lo16(v.z); a5 += q * hi16(v.z);
        a6 += q * lo16(v.w);
    }
#pragma unroll
    for (int q = 8; q >= 1; q >>= 1) {
        a0 += __shfl_xor(a0, q, 16); a1 += __shfl_xor(a1, q, 16);
        a2 += __shfl_xor(a2, q, 16); a3 += __shfl_xor(a3, q, 16);
        a4 += __shfl_xor(a4, q, 16); a5 += __shfl_xor(a5, q, 16);
        a6 += __shfl_xor(a6, q, 16);
    }
    float sc = d1s[n];
    int c0 = 2 * l, c1 = 2 * l + 1;
    float s0 = a0 * sW[c0] + a1 * sW[HH + c0] + a2 * sW[2 * HH + c0]
             + a3 * sW[3 * HH + c0] + a4 * sW[4 * HH + c0]
             + a5 * sW[5 * HH + c0] + a6 * sW[6 * HH + c0];
    float s1 = a0 * sW[c1] + a1 * sW[HH + c1] + a2 * sW[2 * HH + c1]
             + a3 * sW[3 * HH + c1] + a4 * sW[4 * HH + c1]
             + a5 * sW[5 * HH + c1] + a6 * sW[6 * HH + c1];
    x1u[n * 16 + l] = fwd16(pack2(sc * s0 + b1[c0], sc * s1 + b1[c1]));
}

// ---- neighbor max-pool: wave=node, packed u16 max (2 ch/instr) -----------
__global__ __launch_bounds__(256) void k_pool(const int* __restrict__ off,
                                              const int* __restrict__ cnt,
                                              const uint32* __restrict__ spack,
                                              const uint32* __restrict__ X1,
                                              const float* __restrict__ d2,
                                              uint32* __restrict__ xpu,
                                              uint32* __restrict__ xpsu) {
    int t = threadIdx.x;
    int n = blockIdx.x * 4 + (t >> 6);
    int l = t & 63;
    int eg = l >> 2, qt = l & 3;
    int o = off[n], m = cnt[n];
    const uint32* bin = spack + o;
    const uint4* X4 = (const uint4*)X1;
    uint4 u = X4[n * 4 + qt];          // transformed self quarter
    uint32 t0 = u.x, t1 = u.y, t2 = u.z, t3 = u.w;
    for (int j0 = 0; j0 < m; j0 += 16) {
        int j = j0 + eg;
        int r = (j < m) ? (int)(bin[j] & RMASK) : n;   // self = identity
        uint4 v = X4[r * 4 + qt];
        t0 = pkmax(t0, v.x); t1 = pkmax(t1, v.y);
        t2 = pkmax(t2, v.z); t3 = pkmax(t3, v.w);
    }
#pragma unroll
    for (int o2 = 4; o2 < 64; o2 <<= 1) {
        t0 = pkmax(t0, (uint32)__shfl_xor((int)t0, o2, 64));
        t1 = pkmax(t1, (uint32)__shfl_xor((int)t1, o2, 64));
        t2 = pkmax(t2, (uint32)__shfl_xor((int)t2, o2, 64));
        t3 = pkmax(t3, (uint32)__shfl_xor((int)t3, o2, 64));
    }
    if (eg == 0) {
        uint32 r0 = inv16(t0), r1 = inv16(t1), r2 = inv16(t2), r3 = inv16(t3);
        float dn = d2[n];
        uint4 w0, w1;
        w0.x = r0; w0.y = r1; w0.z = r2; w0.w = r3;            // bf16 maxima: exact
        w1.x = pack2(dn * lo16(r0), dn * hi16(r0));
        w1.y = pack2(dn * lo16(r1), dn * hi16(r1));
        w1.z = pack2(dn * lo16(r2), dn * hi16(r2));
        w1.w = pack2(dn * lo16(r3), dn * hi16(r3));
        ((uint4*)xpu)[n * 4 + qt] = w0;
        ((uint4*)xpsu)[n * 4 + qt] = w1;
    }
}

// ---- conv2 gather-sum: wave=node (W2 postponed) --------------------------
__global__ __launch_bounds__(256) void k_agg2(const int* __restrict__ off,
                                              const int* __restrict__ cnt,
                                              const uint32* __restrict__ spack,
                                              const uint32* __restrict__ XPS,
                                              float* __restrict__ Sf) {
    int t = threadIdx.x;
    int n = blockIdx.x * 4 + (t >> 6);
    int l = t & 63;
    int eg = l >> 2, qt = l & 3;
    int o = off[n], m = cnt[n];
    const uint32* bin = spack + o;
    const uint4* X4 = (const uint4*)XPS;
    float a0 = 0, a1 = 0, a2 = 0, a3 = 0, a4 = 0, a5 = 0, a6 = 0, a7 = 0;
    for (int j0 = 0; j0 < m; j0 += 16) {
        int j = j0 + eg;
        if (j < m) {
            uint4 v = X4[(bin[j] & RMASK) * 4 + qt];
            a0 += lo16(v.x); a1 += hi16(v.x);
            a2 += lo16(v.y); a3 += hi16(v.y);
            a4 += lo16(v.z); a5 += hi16(v.z);
            a6 += lo16(v.w); a7 += hi16(v.w);
        }
    }
#pragma unroll
    for (int o2 = 4; o2 < 64; o2 <<= 1) {
        a0 += __shfl_xor(a0, o2, 64); a1 += __shfl_xor(a1, o2, 64);
        a2 += __shfl_xor(a2, o2, 64); a3 += __shfl_xor(a3, o2, 64);
        a4 += __shfl_xor(a4, o2, 64); a5 += __shfl_xor(a5, o2, 64);
        a6 += __shfl_xor(a6, o2, 64); a7 += __shfl_xor(a7, o2, 64);
    }
    if (eg == 0) {
        float4 f0 = make_float4(a0, a1, a2, a3);
        float4 f1 = make_float4(a4, a5, a6, a7);
        ((float4*)Sf)[n * 8 + qt * 2] = f0;
        ((float4*)Sf)[n * 8 + qt * 2 + 1] = f1;
    }
}

// ---- fused: xn-on-the-fly (W2 matvec + relu) + per-graph max + MLP head --
// Uniform per-node work, contiguous reads, no gathers -> no barrier hazard.
// xn value reproduces old k_xn bit-exactly (incl. bf16 round-trip).
__global__ __launch_bounds__(256) void k_gpool_mlp(const float* __restrict__ Sf,
                                                   const uint32* __restrict__ xpu,
                                                   const float* __restrict__ d2,
                                                   const float* __restrict__ b2,
                                                   const float* __restrict__ W2,
                                                   const int* __restrict__ batch,
                                                   const float* __restrict__ Wl1,
                                                   const float* __restrict__ bl1,
                                                   const float* __restrict__ Wl2,
                                                   const float* __restrict__ bl2,
                                                   const float* __restrict__ Wl3,
                                                   const float* __restrict__ bl3,
                                                   float* __restrict__ out) {
    __shared__ float sWc[HH * HH];   // conv W2
    __shared__ float sW1[HH * HH];   // MLP Wl1
    __shared__ float sW2[HH * HH];   // MLP Wl2
    __shared__ float sW3[HH];
    __shared__ float sred[8][HH];
    int t = threadIdx.x;
    int g = blockIdx.x;
    for (int j = t; j < HH * HH; j += 256) {
        sWc[j] = W2[j];
        sW1[j] = Wl1[j];
        sW2[j] = Wl2[j];
    }
    if (t < HH) sW3[t] = Wl3[t];
    __syncthreads();

    int lo = 0, hi = NN;
    while (lo < hi) { int mid = (lo + hi) >> 1; if (batch[mid] < g) lo = mid + 1; else hi = mid; }
    int s = lo;
    hi = NN;
    while (lo < hi) { int mid = (lo + hi) >> 1; if (batch[mid] < g + 1) lo = mid + 1; else hi = mid; }
    int e = lo;

    int c = t & 31, w = t >> 5;
    float bc = b2[c];
    float mx = -3.0e38f;
    for (int i = s + w; i < e; i += 8) {
        float sv = Sf[i * HH + c];              // coalesced 128B per 32-group
        float acc = 0.0f;
#pragma unroll
        for (int k = 0; k < HH; k++) acc += __shfl(sv, k, 32) * sWc[k * HH + c];
        uint32 u = xpu[i * 16 + (c >> 1)];
        float xpv = (c & 1) ? hi16(u) : lo16(u);
        float v = fmaxf(xpv + d2[i] * acc + bc, 0.0f);
        v = b2f(f2b(v));                        // match old k_xn bf16 rounding
        mx = fmaxf(mx, v);
    }
    sred[w][c] = mx;
    __syncthreads();

    if (t < HH) {
        float x0 = sred[0][t];
#pragma unroll
        for (int q = 1; q < 8; q++) x0 = fmaxf(x0, sred[q][t]);
        float acc = 0.0f;
#pragma unroll
        for (int k = 0; k < HH; k++) acc += __shfl(x0, k, 32) * sW1[k * HH + t];
        float a1 = x0 + acc + bl1[t];
        a1 = a1 >= 0.0f ? a1 : SLOPE * a1;
        float acc2 = 0.0f;
#pragma unroll
        for (int k = 0; k < HH; k++) acc2 += __shfl(a1, k, 32) * sW2[k * HH + t];
        float a2 = a1 + acc2 + bl2[t];
        a2 = a2 >= 0.0f ? a2 : SLOPE * a2;
        float p = a2 * sW3[t];
#pragma unroll
        for (int o = 16; o >= 1; o >>= 1) p += __shfl_down(p, o, 32);
        if (t == 0) {
            float o = p + bl3[0];
            o = o >= 0.0f ? o : SLOPE * o;
            out[g] = o;
        }
    }
}

extern "C" void kernel_launch(void* const* d_in, const int* in_sizes, int n_in,
                              void* d_out, int out_size, void* d_ws, size_t ws_size,
                              hipStream_t stream) {
    const float* x   = (const float*)d_in[0];
    const int*   ei  = (const int*)d_in[1];
    const int*   bat = (const int*)d_in[2];
    const float* ew  = (const float*)d_in[3];
    const float* W1  = (const float*)d_in[4];
    const float* b1  = (const float*)d_in[5];
    const float* W2  = (const float*)d_in[6];
    const float* b2  = (const float*)d_in[7];
    const float* Wl1 = (const float*)d_in[8];
    const float* bl1 = (const float*)d_in[9];
    const float* Wl2 = (const float*)d_in[10];
    const float* bl2 = (const float*)d_in[11];
    const float* Wl3 = (const float*)d_in[12];
    const float* bl3 = (const float*)d_in[13];
    float* out = (float*)d_out;

    const int* row = ei;
    const int* col = ei + EE;

    // workspace layout (~46 MB); pay aliased by Sf (pay dead after k_p2)
    char* w = (char*)d_ws;
    uint64* pay  = (uint64*)w;  w += (size_t)P1G * EPB * 8;    // 12.8 MB
    float*  Sf   = (float*)pay;                                 // alias (12.8 MB)
    int*   Pmat  = (int*)w;     w += (size_t)P1G * 392 * 4;    // 1.23 MB
    uint32* spack = (uint32*)w; w += (size_t)NBUK * BCAP * 4;  // 7.2 MB
    int*    cnt  = (int*)w;     w += NN * 4;
    int*    off  = (int*)w;     w += NN * 4;
    float*  d1s  = (float*)w;   w += NN * 4;
    float*  d2   = (float*)w;   w += NN * 4;
    uint32* xsu  = (uint32*)w;  w += (size_t)NN * 4 * 4;       // 1.6 MB
    uint32* x1u  = (uint32*)w;  w += (size_t)NN * 16 * 4;      // 6.4 MB (transformed)
    uint32* xpu  = (uint32*)w;  w += (size_t)NN * 16 * 4;      // 6.4 MB
    uint32* xpsu = (uint32*)w;  w += (size_t)NN * 16 * 4;      // 6.4 MB

    k_p1   <<<P1G, 256, 0, stream>>>(row, col, ew, Pmat, pay);
    k_p2   <<<NBUK, 256, 0, stream>>>(Pmat, pay, x, spack, cnt, off, d1s, d2, xsu);
    k_agg1 <<<NN / 16, 256, 0, stream>>>(off, cnt, spack, (const uint4*)xsu, d1s, b1, W1, x1u);
    k_pool <<<NN / 4, 256, 0, stream>>>(off, cnt, spack, x1u, d2, xpu, xpsu);
    k_agg2 <<<NN / 4, 256, 0, stream>>>(off, cnt, spack, xpsu, Sf);
    k_gpool_mlp<<<GG, 256, 0, stream>>>(Sf, xpu, d2, b2, W2, bat,
                                        Wl1, bl1, Wl2, bl2, Wl3, bl3, out);
}

// Round 15
// 257.437 us; speedup vs baseline: 1.0851x; 1.0205x over previous
//
#include <hip/hip_runtime.h>
#include <hip/hip_bf16.h>

#define NN 100000
#define EE 1600000
#define HH 32
#define GG 512
#define FIN 7
#define NBUK 391        // ceil(NN/256): coarse buckets of 256 nodes
#define EPB 2048        // edges per p1 block
#define P1G 782         // ceil(EE/EPB)
#define BCAP 4608       // per-bucket capacity (mean 4096, +8 sigma)
#define SLOPE 0.22916666666666666f
#define QS 32767.0f
#define IQS (1.0f / 32767.0f)
#define RMASK 0x1FFFFu

typedef unsigned short bf16_t;
typedef unsigned int uint32;
typedef unsigned long long uint64;
typedef unsigned short u16v2 __attribute__((ext_vector_type(2)));

__device__ __forceinline__ bf16_t f2b(float f) {
    return (bf16_t)(__bfloat16_as_ushort(__float2bfloat16(f)));
}
__device__ __forceinline__ float b2f(bf16_t u) {
    return __uint_as_float(((uint32)u) << 16);
}
__device__ __forceinline__ float lo16(uint32 u) { return __uint_as_float(u << 16); }
__device__ __forceinline__ float hi16(uint32 u) { return __uint_as_float(u & 0xFFFF0000u); }
__device__ __forceinline__ uint32 pack2(float a, float b) {
    return (uint32)f2b(a) | ((uint32)f2b(b) << 16);
}
// order-preserving bf16<->u16 transform (per packed pair)
__device__ __forceinline__ uint32 fwd16(uint32 u) {
    return u ^ (0x80008000u | (((u >> 15) & 0x00010001u) * 0x7FFFu));
}
__device__ __forceinline__ uint32 inv16(uint32 w) {
    return w ^ (0x80008000u | ((((~w) >> 15) & 0x00010001u) * 0x7FFFu));
}
__device__ __forceinline__ uint32 pkmax(uint32 a, uint32 b) {
    u16v2 x = __builtin_bit_cast(u16v2, a);
    u16v2 y = __builtin_bit_cast(u16v2, b);
    u16v2 r = __builtin_elementwise_max(x, y);
    return __builtin_bit_cast(uint32, r);
}

// ---- p1: local counting sort by coarse bucket; block-private coalesced dump.
__global__ __launch_bounds__(256) void k_p1(const int* __restrict__ row,
                                            const int* __restrict__ col,
                                            const float* __restrict__ ew,
                                            int* __restrict__ Pmat,
                                            uint64* __restrict__ pay) {
    __shared__ int h[512];
    __shared__ int cur[392];
    int t = threadIdx.x;
    h[t] = 0; h[t + 256] = 0;
    __syncthreads();
    int e0 = blockIdx.x * EPB, e1 = min(e0 + EPB, EE);
    for (int e = e0 + t; e < e1; e += 256) atomicAdd(&h[col[e] >> 8], 1);
    __syncthreads();
    int c0 = h[t], c1 = h[t + 256];
    for (int d = 1; d < 512; d <<= 1) {
        int a = (t >= d) ? h[t - d] : 0;
        int b = h[t + 256 - d];
        __syncthreads();
        h[t] += a; h[t + 256] += b;
        __syncthreads();
    }
    int ex0 = h[t] - c0, ex1 = h[t + 256] - c1;
    if (t < 392) { cur[t] = ex0; Pmat[blockIdx.x * 392 + t] = ex0; }
    if (t + 256 < 392) { cur[t + 256] = ex1; Pmat[blockIdx.x * 392 + t + 256] = ex1; }
    __syncthreads();
    uint64* bpay = pay + (size_t)blockIdx.x * EPB;
    for (int e = e0 + t; e < e1; e += 256) {
        int c = col[e];
        int b = c >> 8;
        uint32 q = (uint32)(ew[e] * QS + 0.5f);
        int r = atomicAdd(&cur[b], 1);             // LDS cursor only
        bpay[r] = ((uint64)(uint32)(c & 255) << 32) | ((uint64)q << 17) | (uint32)row[e];
    }
}

// ---- p2: gather bucket runs via Pmat, in-LDS counting sort -> spack + dis/xsu
__global__ __launch_bounds__(256) void k_p2(const int* __restrict__ Pmat,
                                            const uint64* __restrict__ pay,
                                            const float* __restrict__ x,
                                            uint32* __restrict__ spack,
                                            int* __restrict__ cnt,
                                            int* __restrict__ off,
                                            float* __restrict__ d1s,
                                            float* __restrict__ d2,
                                            uint32* __restrict__ xsu) {
    __shared__ uint64 staged[BCAP];
    __shared__ int hist[256], s[256], cur[256], qsum[256];
    __shared__ int tot;
    int b = blockIdx.x, t = threadIdx.x;
    hist[t] = 0; qsum[t] = 0;
    if (t == 0) tot = 0;
    __syncthreads();
    for (int k = t; k < P1G; k += 256) {
        int s0 = Pmat[k * 392 + b];
        int s1 = Pmat[k * 392 + b + 1];
        int len = s1 - s0;
        if (len > 0) {
            int r0 = atomicAdd(&tot, len);
            const uint64* src = pay + (size_t)k * EPB + s0;
            for (int i = 0; i < len && r0 + i < BCAP; i++) staged[r0 + i] = src[i];
        }
    }
    __syncthreads();
    int M = min(tot, BCAP);
    for (int j = t; j < M; j += 256) atomicAdd(&hist[(int)(staged[j] >> 32)], 1);
    __syncthreads();
    int v = hist[t]; s[t] = v;
    __syncthreads();
    for (int d = 1; d < 256; d <<= 1) {
        int u = (t >= d) ? s[t - d] : 0;
        __syncthreads();
        s[t] += u;
        __syncthreads();
    }
    int excl = s[t] - v;
    int gb = b * BCAP;
    int n = b * 256 + t;
    if (n < NN) { cnt[n] = v; off[n] = gb + excl; }
    cur[t] = excl;
    __syncthreads();
    for (int j = t; j < M; j += 256) {
        uint64 p = staged[j];
        int nb = (int)(p >> 32);
        int r = atomicAdd(&cur[nb], 1);
        spack[gb + r] = (uint32)p;
        atomicAdd(&qsum[nb], (int)((uint32)p >> 17));
    }
    __syncthreads();
    if (n < NN) {
        int sq = qsum[t];
        float dis1 = sq > 0 ? rsqrtf((float)sq * IQS) : 0.0f;
        d1s[n] = dis1 * IQS;
        d2[n] = v > 0 ? rsqrtf((float)v) : 0.0f;
        float f0 = x[n * FIN + 0] * dis1, f1 = x[n * FIN + 1] * dis1;
        float f2 = x[n * FIN + 2] * dis1, f3 = x[n * FIN + 3] * dis1;
        float f4 = x[n * FIN + 4] * dis1, f5 = x[n * FIN + 5] * dis1;
        float f6 = x[n * FIN + 6] * dis1;
        xsu[n * 4 + 0] = pack2(f0, f1);
        xsu[n * 4 + 1] = pack2(f2, f3);
        xsu[n * 4 + 2] = pack2(f4, f5);
        xsu[n * 4 + 3] = pack2(f6, 0.0f);
    }
}

// ---- conv1: lane-per-edge gather; W1 post-sum; x1u written TRANSFORMED ---
__global__ __launch_bounds__(256) void k_agg1(const int* __restrict__ off,
                                              const int* __restrict__ cnt,
                                              const uint32* __restrict__ spack,
                                              const uint4* __restrict__ XS,
                                              const float* __restrict__ d1s,
                                              const float* __restrict__ b1,
                                              const float* __restrict__ W1,
                                              uint32* __restrict__ x1u) {
    __shared__ float sW[FIN * HH];
    int t = threadIdx.x;
    if (t < FIN * HH) sW[t] = W1[t];
    __syncthreads();
    int n = blockIdx.x * 16 + (t >> 4);
    int l = t & 15;
    int o = off[n], m = cnt[n];
    const uint32* bin = spack + o;
    float a0 = 0, a1 = 0, a2 = 0, a3 = 0, a4 = 0, a5 = 0, a6 = 0;
    for (int j = l; j < m; j += 16) {
        uint32 p = bin[j];
        uint4 v = XS[p & RMASK];
        float q = (float)(p >> 17);
        a0 += q * lo16(v.x); a1 += q * hi16(v.x);
        a2 += q * lo16(v.y); a3 += q * hi16(v.y);
        a4 += q * lo16(v.z); a5 += q * hi16(v.z);
        a6 += q * lo16(v.w);
    }
#pragma unroll
    for (int q = 8; q >= 1; q >>= 1) {
        a0 += __shfl_xor(a0, q, 16); a1 += __shfl_xor(a1, q, 16);
        a2 += __shfl_xor(a2, q, 16); a3 += __shfl_xor(a3, q, 16);
        a4 += __shfl_xor(a4, q, 16); a5 += __shfl_xor(a5, q, 16);
        a6 += __shfl_xor(a6, q, 16);
    }
    float sc = d1s[n];
    int c0 = 2 * l, c1 = 2 * l + 1;
    float s0 = a0 * sW[c0] + a1 * sW[HH + c0] + a2 * sW[2 * HH + c0]
             + a3 * sW[3 * HH + c0] + a4 * sW[4 * HH + c0]
             + a5 * sW[5 * HH + c0] + a6 * sW[6 * HH + c0];
    float s1 = a0 * sW[c1] + a1 * sW[HH + c1] + a2 * sW[2 * HH + c1]
             + a3 * sW[3 * HH + c1] + a4 * sW[4 * HH + c1]
             + a5 * sW[5 * HH + c1] + a6 * sW[6 * HH + c1];
    x1u[n * 16 + l] = fwd16(pack2(sc * s0 + b1[c0], sc * s1 + b1[c1]));
}

// ---- neighbor max-pool: wave=node, whole-bin preload + shfl distribution -
__global__ __launch_bounds__(256) void k_pool(const int* __restrict__ off,
                                              const int* __restrict__ cnt,
                                              const uint32* __restrict__ spack,
                                              const uint32* __restrict__ X1,
                                              const float* __restrict__ d2,
                                              uint32* __restrict__ xpu,
                                              uint32* __restrict__ xpsu) {
    int t = threadIdx.x;
    int n = blockIdx.x * 4 + (t >> 6);
    int l = t & 63;
    int eg = l >> 2, qt = l & 3;
    int o = off[n], m = cnt[n];
    const uint32* bin = spack + o;
    const uint4* X4 = (const uint4*)X1;
    uint32 binw = (l < m) ? bin[l] : 0;     // one coalesced load covers bin (m<=64)
    uint4 u = X4[n * 4 + qt];               // transformed self quarter
    uint32 t0 = u.x, t1 = u.y, t2 = u.z, t3 = u.w;
    int mc = min(m, 64);
    for (int j0 = 0; j0 < mc; j0 += 16) {
        int j = j0 + eg;
        uint32 p = (uint32)__shfl((int)binw, j, 64);   // convergent bpermute
        int r = (j < mc) ? (int)(p & RMASK) : n;       // self = identity
        uint4 v = X4[r * 4 + qt];
        t0 = pkmax(t0, v.x); t1 = pkmax(t1, v.y);
        t2 = pkmax(t2, v.z); t3 = pkmax(t3, v.w);
    }
    for (int j0 = 64; j0 < m; j0 += 16) {   // tail: P(m>64) ~ 1e-18, kept for safety
        int j = j0 + eg;
        int r = (j < m) ? (int)(bin[j] & RMASK) : n;
        uint4 v = X4[r * 4 + qt];
        t0 = pkmax(t0, v.x); t1 = pkmax(t1, v.y);
        t2 = pkmax(t2, v.z); t3 = pkmax(t3, v.w);
    }
#pragma unroll
    for (int o2 = 4; o2 < 64; o2 <<= 1) {
        t0 = pkmax(t0, (uint32)__shfl_xor((int)t0, o2, 64));
        t1 = pkmax(t1, (uint32)__shfl_xor((int)t1, o2, 64));
        t2 = pkmax(t2, (uint32)__shfl_xor((int)t2, o2, 64));
        t3 = pkmax(t3, (uint32)__shfl_xor((int)t3, o2, 64));
    }
    if (eg == 0) {
        uint32 r0 = inv16(t0), r1 = inv16(t1), r2 = inv16(t2), r3 = inv16(t3);
        float dn = d2[n];
        uint4 w0, w1;
        w0.x = r0; w0.y = r1; w0.z = r2; w0.w = r3;            // bf16 maxima: exact
        w1.x = pack2(dn * lo16(r0), dn * hi16(r0));
        w1.y = pack2(dn * lo16(r1), dn * hi16(r1));
        w1.z = pack2(dn * lo16(r2), dn * hi16(r2));
        w1.w = pack2(dn * lo16(r3), dn * hi16(r3));
        ((uint4*)xpu)[n * 4 + qt] = w0;
        ((uint4*)xpsu)[n * 4 + qt] = w1;
    }
}

// ---- conv2 gather-sum: wave=node, whole-bin preload (W2 postponed) -------
__global__ __launch_bounds__(256) void k_agg2(const int* __restrict__ off,
                                              const int* __restrict__ cnt,
                                              const uint32* __restrict__ spack,
                                              const uint32* __restrict__ XPS,
                                              float* __restrict__ Sf) {
    int t = threadIdx.x;
    int n = blockIdx.x * 4 + (t >> 6);
    int l = t & 63;
    int eg = l >> 2, qt = l & 3;
    int o = off[n], m = cnt[n];
    const uint32* bin = spack + o;
    const uint4* X4 = (const uint4*)XPS;
    uint32 binw = (l < m) ? bin[l] : 0;     // whole-bin preload
    float a0 = 0, a1 = 0, a2 = 0, a3 = 0, a4 = 0, a5 = 0, a6 = 0, a7 = 0;
    int mc = min(m, 64);
    for (int j0 = 0; j0 < mc; j0 += 16) {
        int j = j0 + eg;
        uint32 p = (uint32)__shfl((int)binw, j, 64);
        if (j < mc) {
            uint4 v = X4[(p & RMASK) * 4 + qt];
            a0 += lo16(v.x); a1 += hi16(v.x);
            a2 += lo16(v.y); a3 += hi16(v.y);
            a4 += lo16(v.z); a5 += hi16(v.z);
            a6 += lo16(v.w); a7 += hi16(v.w);
        }
    }
    for (int j0 = 64; j0 < m; j0 += 16) {   // tail, vanishingly rare
        int j = j0 + eg;
        if (j < m) {
            uint4 v = X4[(bin[j] & RMASK) * 4 + qt];
            a0 += lo16(v.x); a1 += hi16(v.x);
            a2 += lo16(v.y); a3 += hi16(v.y);
            a4 += lo16(v.z); a5 += hi16(v.z);
            a6 += lo16(v.w); a7 += hi16(v.w);
        }
    }
#pragma unroll
    for (int o2 = 4; o2 < 64; o2 <<= 1) {
        a0 += __shfl_xor(a0, o2, 64); a1 += __shfl_xor(a1, o2, 64);
        a2 += __shfl_xor(a2, o2, 64); a3 += __shfl_xor(a3, o2, 64);
        a4 += __shfl_xor(a4, o2, 64); a5 += __shfl_xor(a5, o2, 64);
        a6 += __shfl_xor(a6, o2, 64); a7 += __shfl_xor(a7, o2, 64);
    }
    if (eg == 0) {
        float4 f0 = make_float4(a0, a1, a2, a3);
        float4 f1 = make_float4(a4, a5, a6, a7);
        ((float4*)Sf)[n * 8 + qt * 2] = f0;
        ((float4*)Sf)[n * 8 + qt * 2 + 1] = f1;
    }
}

// ---- fused: xn-on-the-fly (W2 matvec + relu) + per-graph max + MLP head --
__global__ __launch_bounds__(256) void k_gpool_mlp(const float* __restrict__ Sf,
                                                   const uint32* __restrict__ xpu,
                                                   const float* __restrict__ d2,
                                                   const float* __restrict__ b2,
                                                   const float* __restrict__ W2,
                                                   const int* __restrict__ batch,
                                                   const float* __restrict__ Wl1,
                                                   const float* __restrict__ bl1,
                                                   const float* __restrict__ Wl2,
                                                   const float* __restrict__ bl2,
                                                   const float* __restrict__ Wl3,
                                                   const float* __restrict__ bl3,
                                                   float* __restrict__ out) {
    __shared__ float sWc[HH * HH];   // conv W2
    __shared__ float sW1[HH * HH];   // MLP Wl1
    __shared__ float sW2[HH * HH];   // MLP Wl2
    __shared__ float sW3[HH];
    __shared__ float sred[8][HH];
    int t = threadIdx.x;
    int g = blockIdx.x;
    for (int j = t; j < HH * HH; j += 256) {
        sWc[j] = W2[j];
        sW1[j] = Wl1[j];
        sW2[j] = Wl2[j];
    }
    if (t < HH) sW3[t] = Wl3[t];
    __syncthreads();

    int lo = 0, hi = NN;
    while (lo < hi) { int mid = (lo + hi) >> 1; if (batch[mid] < g) lo = mid + 1; else hi = mid; }
    int s = lo;
    hi = NN;
    while (lo < hi) { int mid = (lo + hi) >> 1; if (batch[mid] < g + 1) lo = mid + 1; else hi = mid; }
    int e = lo;

    int c = t & 31, w = t >> 5;
    float bc = b2[c];
    float mx = -3.0e38f;
    for (int i = s + w; i < e; i += 8) {
        float sv = Sf[i * HH + c];              // coalesced 128B per 32-group
        float acc = 0.0f;
#pragma unroll
        for (int k = 0; k < HH; k++) acc += __shfl(sv, k, 32) * sWc[k * HH + c];
        uint32 u = xpu[i * 16 + (c >> 1)];
        float xpv = (c & 1) ? hi16(u) : lo16(u);
        float v = fmaxf(xpv + d2[i] * acc + bc, 0.0f);
        v = b2f(f2b(v));                        // match old k_xn bf16 rounding
        mx = fmaxf(mx, v);
    }
    sred[w][c] = mx;
    __syncthreads();

    if (t < HH) {
        float x0 = sred[0][t];
#pragma unroll
        for (int q = 1; q < 8; q++) x0 = fmaxf(x0, sred[q][t]);
        float acc = 0.0f;
#pragma unroll
        for (int k = 0; k < HH; k++) acc += __shfl(x0, k, 32) * sW1[k * HH + t];
        float a1 = x0 + acc + bl1[t];
        a1 = a1 >= 0.0f ? a1 : SLOPE * a1;
        float acc2 = 0.0f;
#pragma unroll
        for (int k = 0; k < HH; k++) acc2 += __shfl(a1, k, 32) * sW2[k * HH + t];
        float a2 = a1 + acc2 + bl2[t];
        a2 = a2 >= 0.0f ? a2 : SLOPE * a2;
        float p = a2 * sW3[t];
#pragma unroll
        for (int o = 16; o >= 1; o >>= 1) p += __shfl_down(p, o, 32);
        if (t == 0) {
            float o = p + bl3[0];
            o = o >= 0.0f ? o : SLOPE * o;
            out[g] = o;
        }
    }
}

extern "C" void kernel_launch(void* const* d_in, const int* in_sizes, int n_in,
                              void* d_out, int out_size, void* d_ws, size_t ws_size,
                              hipStream_t stream) {
    const float* x   = (const float*)d_in[0];
    const int*   ei  = (const int*)d_in[1];
    const int*   bat = (const int*)d_in[2];
    const float* ew  = (const float*)d_in[3];
    const float* W1  = (const float*)d_in[4];
    const float* b1  = (const float*)d_in[5];
    const float* W2  = (const float*)d_in[6];
    const float* b2  = (const float*)d_in[7];
    const float* Wl1 = (const float*)d_in[8];
    const float* bl1 = (const float*)d_in[9];
    const float* Wl2 = (const float*)d_in[10];
    const float* bl2 = (const float*)d_in[11];
    const float* Wl3 = (const float*)d_in[12];
    const float* bl3 = (const float*)d_in[13];
    float* out = (float*)d_out;

    const int* row = ei;
    const int* col = ei + EE;

    // workspace layout (~46 MB); pay aliased by Sf (pay dead after k_p2)
    char* w = (char*)d_ws;
    uint64* pay  = (uint64*)w;  w += (size_t)P1G * EPB * 8;    // 12.8 MB
    float*  Sf   = (float*)pay;                                 // alias (12.8 MB)
    int*   Pmat  = (int*)w;     w += (size_t)P1G * 392 * 4;    // 1.23 MB
    uint32* spack = (uint32*)w; w += (size_t)NBUK * BCAP * 4;  // 7.2 MB
    int*    cnt  = (int*)w;     w += NN * 4;
    int*    off  = (int*)w;     w += NN * 4;
    float*  d1s  = (float*)w;   w += NN * 4;
    float*  d2   = (float*)w;   w += NN * 4;
    uint32* xsu  = (uint32*)w;  w += (size_t)NN * 4 * 4;       // 1.6 MB
    uint32* x1u  = (uint32*)w;  w += (size_t)NN * 16 * 4;      // 6.4 MB (transformed)
    uint32* xpu  = (uint32*)w;  w += (size_t)NN * 16 * 4;      // 6.4 MB
    uint32* xpsu = (uint32*)w;  w += (size_t)NN * 16 * 4;      // 6.4 MB

    k_p1   <<<P1G, 256, 0, stream>>>(row, col, ew, Pmat, pay);
    k_p2   <<<NBUK, 256, 0, stream>>>(Pmat, pay, x, spack, cnt, off, d1s, d2, xsu);
    k_agg1 <<<NN / 16, 256, 0, stream>>>(off, cnt, spack, (const uint4*)xsu, d1s, b1, W1, x1u);
    k_pool <<<NN / 4, 256, 0, stream>>>(off, cnt, spack, x1u, d2, xpu, xpsu);
    k_agg2 <<<NN / 4, 256, 0, stream>>>(off, cnt, spack, xpsu, Sf);
    k_gpool_mlp<<<GG, 256, 0, stream>>>(Sf, xpu, d2, b2, W2, bat,
                                        Wl1, bl1, Wl2, bl2, Wl3, bl3, out);
}